// Round 10
// baseline (589.190 us; speedup 1.0000x reference)
//
#include <hip/hip_runtime.h>
#include <hip/hip_bf16.h>
#include <stdint.h>

// ---------------------------------------------------------------------------
// SelfAttention: QKV = X@W + b ; S = QK^T/32 (mask -> -inf) ; O = softmax(S)@V
// B=4, S=2048, H=1024.  bf16 MFMA path.
// R18: prep kernel + ONE fused persistent GEMM kernel (regular launches; R17's
//     cooperative launch returned zeros => launch rejected by harness).
//     Budget analysis: scores has ~544 active tiles on a 512-slot machine ->
//     2 full rounds (~53us for ~27us of work). Fused kernel: global ticket
//     (qkv tiles 0..1535, scores 1536..2559, pv 2560..3071) + per-strip
//     dependency counters (qdone/kdone/vdone/sdone) with release-publish /
//     relaxed-spin + acquire-fence. Deadlock-free for any residency: every
//     ticket's deps hold strictly smaller tickets. Removes 2 boundaries,
//     tails, and the scores quantization (finished qkv blocks stream into
//     ready scores tiles, then pv).
//     GEMM tile bodies = R16 verbatim (best passing: 191.7us).
// ---------------------------------------------------------------------------

typedef __attribute__((ext_vector_type(8))) short bf16x8;   // 8 bf16 = 4 VGPRs
typedef __attribute__((ext_vector_type(4))) float f32x4;

__device__ __forceinline__ void async_cp16(const void* g, void* l) {
  __builtin_amdgcn_global_load_lds(
      (const __attribute__((address_space(1))) void*)g,
      (__attribute__((address_space(3))) void*)l, 16, 0, 0);
}

__device__ __forceinline__ uint32_t laddr(const void* p) {
  return (uint32_t)(uintptr_t)(const __attribute__((address_space(3))) void*)p;
}

#define FENCE() asm volatile("" ::: "memory")
#define BAR()                           \
  do {                                  \
    FENCE();                            \
    __builtin_amdgcn_s_barrier();       \
    FENCE();                            \
  } while (0)
#define VMW(N) asm volatile("s_waitcnt vmcnt(" #N ")" ::: "memory")
#define LGKM0()                                            \
  do {                                                     \
    asm volatile("s_waitcnt lgkmcnt(0)" ::: "memory");     \
    __builtin_amdgcn_sched_barrier(0);                     \
  } while (0)
// asm ds_read_b128 with literal byte offset; no memory operand on purpose.
#define DSR(dst, a, OFF) \
  asm volatile("ds_read_b128 %0, %1 offset:" #OFF : "=v"(dst) : "v"(a))

// k-loop building blocks (bind to locals in each tile handler).
#define STAGE(BUF, k0)                                            \
  do {                                                            \
    _Pragma("unroll") for (int cc = 0; cc < 8; ++cc)              \
        async_cp16(gsrc[cc] + (k0), ls + (BUF)*16384 + loff[cc]); \
  } while (0)
#define COMP(BUF)                                                             \
  do {                                                                        \
    _Pragma("unroll") for (int w = 0; w < 2; ++w) {                           \
      DSR(af[0], aAd[BUF][w], 0);                                             \
      DSR(af[1], aAd[BUF][w], 2048);                                          \
      DSR(af[2], aAd[BUF][w], 4096);                                          \
      DSR(af[3], aAd[BUF][w], 6144);                                          \
      DSR(bf[0], bBd[BUF][w], 0);                                             \
      DSR(bf[1], bBd[BUF][w], 2048);                                          \
      DSR(bf[2], bBd[BUF][w], 4096);                                          \
      DSR(bf[3], bBd[BUF][w], 6144);                                          \
      LGKM0();                                                                \
      _Pragma("unroll") for (int mi = 0; mi < 4; ++mi)                        \
          _Pragma("unroll") for (int ni = 0; ni < 4; ++ni) acc[mi][ni] =      \
              __builtin_amdgcn_mfma_f32_16x16x32_bf16(af[mi], bf[ni],         \
                                                      acc[mi][ni], 0, 0, 0);  \
    }                                                                         \
  } while (0)

// sync[] layout (ints): 0 ticket; 1+z*16+m qdone (tgt 8); 65+z*16+kb kdone
// (tgt 8); 129+z*8+db vdone (tgt np); 161+z*16+m sdone (tgt np).
__device__ __forceinline__ void wait_ge(int* p, int target) {
  while (__hip_atomic_load(p, __ATOMIC_RELAXED, __HIP_MEMORY_SCOPE_AGENT) <
         target)
    __builtin_amdgcn_s_sleep(4);
}

// ------------------- prep: cvt + W^T + mask + zero --------------------------
// grid: [0,8192) X cvt; [8192,11264) W transpose; [11264,11268) mask+rowsum0;
//       11268 zero sync counters.
__global__ __launch_bounds__(256) void prep(
    const float* __restrict__ X, __hip_bfloat16* __restrict__ Xb,
    const float* __restrict__ W, __hip_bfloat16* __restrict__ Wt,
    const int* __restrict__ mask, int* __restrict__ idx,
    int* __restrict__ cnt, int* __restrict__ cnt_pad,
    float* __restrict__ rowsum, int* __restrict__ gsync) {
  const int b = blockIdx.x;
  const int tid = threadIdx.x;
  if (b < 8192) {
    int i = (b * 256 + tid) * 4;
    float4 f = *(const float4*)(X + i);
    __hip_bfloat16 o[4];
    o[0] = __float2bfloat16(f.x);
    o[1] = __float2bfloat16(f.y);
    o[2] = __float2bfloat16(f.z);
    o[3] = __float2bfloat16(f.w);
    *(ushort4*)(Xb + i) = *(const ushort4*)o;
    return;
  }
  if (b < 11264) {
    __shared__ float tile[32][33];
    const int t = b - 8192;
    const int bx = (t % 96) * 32;   // src col (of 3072)
    const int by = (t / 96) * 32;   // src row (of 1024)
    const int tx = tid & 31, ty = tid >> 5;
#pragma unroll
    for (int j = 0; j < 4; ++j)
      tile[ty + j * 8][tx] = W[(int64_t)(by + ty + j * 8) * 3072 + bx + tx];
    __syncthreads();
#pragma unroll
    for (int j = 0; j < 4; ++j)
      Wt[(int64_t)(bx + ty + j * 8) * 1024 + by + tx] =
          __float2bfloat16(tile[tx][ty + j * 8]);
    return;
  }
  if (b < 11268) {
    const int z = b - 11264;
    const int* mz = mask + z * 2048;
    int* iz = idx + z * 2048;
    const int lane = tid & 63, wave = tid >> 6;
    float* rs = rowsum + z * 2048;
#pragma unroll
    for (int j = 0; j < 8; ++j) rs[tid + j * 256] = 0.f;

    int keep[8];
    int local = 0;
#pragma unroll
    for (int j = 0; j < 8; ++j) {
      keep[j] = (mz[tid * 8 + j] == 0);
      local += keep[j];
    }
    int pre = local;  // inclusive wave scan
#pragma unroll
    for (int off = 1; off <= 32; off <<= 1) {
      int n = __shfl_up(pre, off, 64);
      if (lane >= off) pre += n;
    }
    __shared__ int wsum[4];
    if (lane == 63) wsum[wave] = pre;
    __syncthreads();
    int base = 0;
    for (int w = 0; w < wave; ++w) base += wsum[w];
    int excl = base + pre - local;
#pragma unroll
    for (int j = 0; j < 8; ++j)
      if (keep[j]) iz[excl++] = tid * 8 + j;
    if (tid == 255) {
      int tot = base + pre;
      cnt[z] = tot;
      cnt_pad[z] = (tot + 127) & ~127;
    }
    return;
  }
  gsync[tid] = 0;  // b == 11268, 256 ints
}

// --------------------------- fused GEMM kernel ------------------------------
__global__ __launch_bounds__(256) void fused(
    const __hip_bfloat16* __restrict__ Xb, const __hip_bfloat16* __restrict__ Wt,
    const float* __restrict__ bias, const int* __restrict__ idx,
    const int* __restrict__ cnt, const int* __restrict__ cnt_pad,
    __hip_bfloat16* __restrict__ Q, __hip_bfloat16* __restrict__ Kc,
    __hip_bfloat16* __restrict__ Vt, __hip_bfloat16* __restrict__ Sc,
    float* __restrict__ rowsum, float* __restrict__ out, float scale2,
    int* __restrict__ gsync) {
  __shared__ __hip_bfloat16 ls[32768];  // 64KB dbuf; qkv V-epi uses 17408 el
  const int tid = threadIdx.x;
  const int wave = tid >> 6, lane = tid & 63;
  const int quad = lane >> 4, tr = lane & 15, t7 = tr & 7;
  const int wm = wave & 1, wn = wave >> 1;
  const int srow = lane >> 3;
  const int kcs = ((lane & 7) ^ srow) * 8;  // pre-swizzled k-chunk (elements)

  uint32_t aAd[2][2], bBd[2][2];
  {
    uint32_t base = laddr(ls);
#pragma unroll
    for (int b = 0; b < 2; ++b)
#pragma unroll
      for (int w = 0; w < 2; ++w) {
        uint32_t col = (uint32_t)(((((w << 2) | quad)) ^ t7) * 16);
        aAd[b][w] = base + b * 32768 + (wm * 64 + tr) * 128 + col;
        bBd[b][w] = base + b * 32768 + 16384 + (wn * 64 + tr) * 128 + col;
      }
  }

  for (;;) {
    __syncthreads();  // prior tile's LDS use done; ls[0] reusable
    if (tid == 0) {
      int tt = __hip_atomic_fetch_add(&gsync[0], 1, __ATOMIC_RELAXED,
                                      __HIP_MEMORY_SCOPE_AGENT);
      *(int*)ls = tt;
    }
    __syncthreads();
    const int t = *(const int*)ls;
    __syncthreads();  // reads done before STAGE overwrites ls
    if (t >= 3072) break;

    if (t < 1536) {
      // ------------------------------ qkv tile -----------------------------
      const int z = t / 384, f = t % 384;
      const int xcd = f & 7, loc = f >> 3;
      const int m0 = ((loc & 7) * 2 + (xcd >> 2)) * 128;
      const int n_idx = (loc >> 3) * 4 + (xcd & 3);
      const bool isQ = (n_idx < 8);
      if (!isQ && m0 >= cnt_pad[z]) continue;
      const int n0 = (isQ ? n_idx : n_idx - 8) * 128;
      const __hip_bfloat16* A = Xb + (int64_t)z * 2048 * 1024;
      const __hip_bfloat16* Bt = Wt + (isQ ? 0 : (int64_t)1024 * 1024);
      const float* bv = bias + (isQ ? 0 : 1024);

      const __hip_bfloat16* gsrc[8];
      int loff[8];
      {
        const int cz = isQ ? 0 : cnt[z];
        const int* idxz = idx + z * 2048;
#pragma unroll
        for (int cc = 0; cc < 8; ++cc) {
          int c = wave * 8 + cc;
          int isA = (c < 16);
          int cr = isA ? c : (c - 16);
          int row = cr * 8 + srow;
          if (isA) {
            int ar = m0 + row;
            if (!isQ) ar = (ar < cz) ? idxz[ar] : 0;
            gsrc[cc] = A + (int64_t)ar * 1024 + kcs;
          } else {
            gsrc[cc] = Bt + (int64_t)(n0 + row) * 1024 + kcs;
          }
          loff[cc] = (isA ? 0 : 8192) + cr * 512;
        }
      }

      f32x4 acc[4][4];
#pragma unroll
      for (int mi = 0; mi < 4; ++mi)
#pragma unroll
        for (int ni = 0; ni < 4; ++ni)
          acc[mi][ni] = (f32x4){0.f, 0.f, 0.f, 0.f};
      bf16x8 af[4], bf[4];

      STAGE(0, 0);
      for (int it = 0; it < 8; ++it) {
        STAGE(1, (2 * it + 1) * 64);
        VMW(8); BAR();
        COMP(0);
        BAR();
        if (it < 7) {
          STAGE(0, (2 * it + 2) * 64);
          VMW(8);
        } else {
          VMW(0);
        }
        BAR();
        COMP(1);
        BAR();
      }

      const int rowbase = m0 + wm * 64;
      const int colbase = n0 + wn * 64;
      if (isQ) {
        __hip_bfloat16* C = Q + (int64_t)z * 2048 * 1024;
#pragma unroll
        for (int ni = 0; ni < 4; ++ni) {
          int col = colbase + ni * 16 + tr;
          float bb = bv[col];
#pragma unroll
          for (int mi = 0; mi < 4; ++mi) {
            int row = rowbase + mi * 16 + quad * 4;
#pragma unroll
            for (int r = 0; r < 4; ++r)
              C[(int64_t)(row + r) * 1024 + col] =
                  __float2bfloat16(acc[mi][ni][r] + bb);
          }
        }
      } else if (n0 < 1024) {  // K half
        __hip_bfloat16* C = Kc + (int64_t)z * 2048 * 1024;
#pragma unroll
        for (int ni = 0; ni < 4; ++ni) {
          int col = colbase + ni * 16 + tr;
          float bb = bv[col];
#pragma unroll
          for (int mi = 0; mi < 4; ++mi) {
            int row = rowbase + mi * 16 + quad * 4;
#pragma unroll
            for (int r = 0; r < 4; ++r)
              C[(int64_t)(row + r) * 1024 + col] =
                  __float2bfloat16(acc[mi][ni][r] + bb);
          }
        }
      } else {  // V half -> LDS transpose -> coalesced Vt rows
        __syncthreads();
#pragma unroll
        for (int ni = 0; ni < 4; ++ni) {
          int cl = wn * 64 + ni * 16 + tr;
          float bb = bv[colbase + ni * 16 + tr];
#pragma unroll
          for (int mi = 0; mi < 4; ++mi) {
            int rl = wm * 64 + mi * 16 + quad * 4;
            __hip_bfloat16 h[4];
#pragma unroll
            for (int r = 0; r < 4; ++r)
              h[r] = __float2bfloat16(acc[mi][ni][r] + bb);
            *(ushort4*)(ls + cl * 136 + rl) = *(const ushort4*)h;
          }
        }
        __syncthreads();
        __hip_bfloat16* Vz = Vt + (int64_t)z * 1024 * 2048;
        const int d0 = n0 - 1024;
        const int seg = tid & 15;
#pragma unroll
        for (int p = 0; p < 8; ++p) {
          int d = p * 16 + (tid >> 4);
          bf16x8 v = *(const bf16x8*)(ls + d * 136 + seg * 8);
          *(bf16x8*)(Vz + (int64_t)(d0 + d) * 2048 + m0 + seg * 8) = v;
        }
      }
      // publish
      __threadfence();
      __syncthreads();
      if (tid == 0) {
        int* p = isQ ? &gsync[1 + z * 16 + (m0 >> 7)]
                     : (n0 < 1024 ? &gsync[65 + z * 16 + (m0 >> 7)]
                                  : &gsync[129 + z * 8 + ((n0 - 1024) >> 7)]);
        __hip_atomic_fetch_add(p, 1, __ATOMIC_RELEASE,
                               __HIP_MEMORY_SCOPE_AGENT);
      }
    } else if (t < 2560) {
      // ----------------------------- scores tile ---------------------------
      const int t2 = t - 1536;
      const int z = t2 >> 8, f = t2 & 255;
      const int xcd = f & 7, loc = f >> 3;
      const int m0 = ((loc & 7) * 2 + (xcd >> 2)) * 128;
      const int n0 = ((loc >> 3) * 4 + (xcd & 3)) * 128;
      if (n0 >= cnt_pad[z]) continue;
      if (tid == 0) {
        wait_ge(&gsync[1 + z * 16 + (m0 >> 7)], 8);    // Q row-strip done
        wait_ge(&gsync[65 + z * 16 + (n0 >> 7)], 8);   // K key-block done
      }
      __syncthreads();
      __threadfence();  // acquire: invalidate caches before reading Q/Kc

      const __hip_bfloat16* A = Q + (int64_t)z * 2048 * 1024;
      const __hip_bfloat16* Bt = Kc + (int64_t)z * 2048 * 1024;

      const __hip_bfloat16* gsrc[8];
      int loff[8];
      {
#pragma unroll
        for (int cc = 0; cc < 8; ++cc) {
          int c = wave * 8 + cc;
          int isA = (c < 16);
          int cr = isA ? c : (c - 16);
          int row = cr * 8 + srow;
          gsrc[cc] = isA ? (A + (int64_t)(m0 + row) * 1024 + kcs)
                         : (Bt + (int64_t)(n0 + row) * 1024 + kcs);
          loff[cc] = (isA ? 0 : 8192) + cr * 512;
        }
      }

      f32x4 acc[4][4];
#pragma unroll
      for (int mi = 0; mi < 4; ++mi)
#pragma unroll
        for (int ni = 0; ni < 4; ++ni)
          acc[mi][ni] = (f32x4){0.f, 0.f, 0.f, 0.f};
      bf16x8 af[4], bf[4];

      STAGE(0, 0);
      for (int it = 0; it < 8; ++it) {
        STAGE(1, (2 * it + 1) * 64);
        VMW(8); BAR();
        COMP(0);
        BAR();
        if (it < 7) {
          STAGE(0, (2 * it + 2) * 64);
          VMW(8);
        } else {
          VMW(0);
        }
        BAR();
        COMP(1);
        BAR();
      }

      const int rowbase = m0 + wm * 64;
      const int colbase = n0 + wn * 64;
      const int cn = cnt[z];
      __hip_bfloat16* C = Sc + (int64_t)z * 2048 * 2048;

      float psum[4][4];
#pragma unroll
      for (int mi = 0; mi < 4; ++mi)
#pragma unroll
        for (int r = 0; r < 4; ++r) psum[mi][r] = 0.f;

#pragma unroll
      for (int ni = 0; ni < 4; ++ni) {
        int col = colbase + ni * 16 + tr;
        bool valid = (col < cn);
#pragma unroll
        for (int mi = 0; mi < 4; ++mi) {
          int row = rowbase + mi * 16 + quad * 4;
#pragma unroll
          for (int r = 0; r < 4; ++r) {
            float e = valid ? exp2f(acc[mi][ni][r] * scale2) : 0.f;
            C[(int64_t)(row + r) * 2048 + col] = __float2bfloat16(e);
            psum[mi][r] += e;
          }
        }
      }
#pragma unroll
      for (int off = 1; off <= 8; off <<= 1)
#pragma unroll
        for (int mi = 0; mi < 4; ++mi)
#pragma unroll
          for (int r = 0; r < 4; ++r)
            psum[mi][r] += __shfl_xor(psum[mi][r], off, 64);
      if (tr == 0) {
        float* rs = rowsum + z * 2048 + rowbase;
#pragma unroll
        for (int mi = 0; mi < 4; ++mi)
#pragma unroll
          for (int r = 0; r < 4; ++r)
            atomicAdd(&rs[mi * 16 + quad * 4 + r], psum[mi][r]);
      }
      // publish scores row-strip progress
      __threadfence();
      __syncthreads();
      if (tid == 0)
        __hip_atomic_fetch_add(&gsync[161 + z * 16 + (m0 >> 7)], 1,
                               __ATOMIC_RELEASE, __HIP_MEMORY_SCOPE_AGENT);
    } else {
      // ------------------------------- pv tile -----------------------------
      const int t3 = t - 2560;
      const int z = t3 >> 7, f = t3 & 127;
      const int xcd = f & 7, loc = f >> 3;
      const int m0 = ((loc & 7) * 2 + (xcd >> 2)) * 128;
      const int n0 = ((loc >> 3) * 4 + (xcd & 3)) * 128;
      const int Ks = cnt_pad[z];
      const int np = Ks >> 7;
      if (tid == 0) {
        wait_ge(&gsync[161 + z * 16 + (m0 >> 7)], np);  // all scores of row
        wait_ge(&gsync[129 + z * 8 + (n0 >> 7)], np);   // all V for d-block
      }
      __syncthreads();
      __threadfence();

      const __hip_bfloat16* A = Sc + (int64_t)z * 2048 * 2048;
      const __hip_bfloat16* Bt = Vt + (int64_t)z * 1024 * 2048;

      const __hip_bfloat16* gsrc[8];
      int loff[8];
      {
#pragma unroll
        for (int cc = 0; cc < 8; ++cc) {
          int c = wave * 8 + cc;
          int isA = (c < 16);
          int cr = isA ? c : (c - 16);
          int row = cr * 8 + srow;
          gsrc[cc] = isA ? (A + (int64_t)(m0 + row) * 2048 + kcs)
                         : (Bt + (int64_t)(n0 + row) * 2048 + kcs);
          loff[cc] = (isA ? 0 : 8192) + cr * 512;
        }
      }

      f32x4 acc[4][4];
#pragma unroll
      for (int mi = 0; mi < 4; ++mi)
#pragma unroll
        for (int ni = 0; ni < 4; ++ni)
          acc[mi][ni] = (f32x4){0.f, 0.f, 0.f, 0.f};
      bf16x8 af[4], bf[4];

      STAGE(0, 0);
      for (int it = 0; it < np; ++it) {
        STAGE(1, (2 * it + 1) * 64);
        VMW(8); BAR();
        COMP(0);
        BAR();
        if (it + 1 < np) {
          STAGE(0, (2 * it + 2) * 64);
          VMW(8);
        } else {
          VMW(0);
        }
        BAR();
        COMP(1);
        BAR();
      }

      const int rowbase = m0 + wm * 64;
      const int colbase = n0 + wn * 64;
      const float* rs = rowsum + z * 2048 + rowbase;
      float invv[4][4];
#pragma unroll
      for (int mi = 0; mi < 4; ++mi)
#pragma unroll
        for (int r = 0; r < 4; ++r)
          invv[mi][r] = 1.0f / rs[mi * 16 + quad * 4 + r];

      float* C = out + (int64_t)z * 2048 * 1024;
#pragma unroll
      for (int ni = 0; ni < 4; ++ni) {
        int col = colbase + ni * 16 + tr;
#pragma unroll
        for (int mi = 0; mi < 4; ++mi) {
          int row = rowbase + mi * 16 + quad * 4;
#pragma unroll
          for (int r = 0; r < 4; ++r)
            C[(int64_t)(row + r) * 1024 + col] = acc[mi][ni][r] * invv[mi][r];
        }
      }
    }
  }
}

// ------------------------------- launcher ----------------------------------
extern "C" void kernel_launch(void* const* d_in, const int* in_sizes, int n_in,
                              void* d_out, int out_size, void* d_ws,
                              size_t ws_size, hipStream_t stream) {
  const float* X = (const float*)d_in[0];        // (4,2048,1024) fp32
  const int* mask = (const int*)d_in[1];         // (4,2048) bool->int32
  const float* W = (const float*)d_in[2];        // (1024,3072) fp32
  const float* bias = (const float*)d_in[3];     // (3072,) fp32
  float* out = (float*)d_out;                    // (4,2048,1024) fp32

  char* ws = (char*)d_ws;
  auto alloc = [&](size_t bytes) {
    char* p = ws;
    ws += (bytes + 255) & ~(size_t)255;
    return p;
  };
  __hip_bfloat16* Xb = (__hip_bfloat16*)alloc(8192ULL * 1024 * 2);      // 16.8 MB
  __hip_bfloat16* Wt = (__hip_bfloat16*)alloc(3072ULL * 1024 * 2);      //  6.3 MB
  __hip_bfloat16* Q = (__hip_bfloat16*)alloc(8192ULL * 1024 * 2);       // 16.8 MB
  __hip_bfloat16* Kc = (__hip_bfloat16*)alloc(4ULL * 2048 * 1024 * 2);  // 16.8 MB
  __hip_bfloat16* Vt = (__hip_bfloat16*)alloc(4ULL * 1024 * 2048 * 2);  // 16.8 MB
  __hip_bfloat16* Sc = (__hip_bfloat16*)alloc(4ULL * 2048 * 2048 * 2);  // 33.6 MB
  float* rowsum = (float*)alloc(8192ULL * 4);                           // 32 KB
  int* idx = (int*)alloc(4ULL * 2048 * 4);
  int* cnt = (int*)alloc(64);
  int* cnt_pad = (int*)alloc(64);
  int* gsync = (int*)alloc(256 * 4);

  // 1) prep: X->bf16, W->W^T bf16, mask->index list, rowsum=0, sync=0
  prep<<<11269, 256, 0, stream>>>(X, Xb, W, Wt, mask, idx, cnt, cnt_pad,
                                  rowsum, gsync);
  // 2) fused persistent qkv+scores+pv with ticket + dependency counters
  fused<<<512, 256, 0, stream>>>(Xb, Wt, bias, idx, cnt, cnt_pad, Q, Kc, Vt,
                                 Sc, rowsum, out,
                                 0.03125f * 1.4426950408889634f, gsync);
}

// Round 11
// 201.484 us; speedup vs baseline: 2.9243x; 2.9243x over previous
//
#include <hip/hip_runtime.h>
#include <hip/hip_bf16.h>
#include <stdint.h>

// ---------------------------------------------------------------------------
// SelfAttention: QKV = X@W + b ; S = QK^T/32 (mask -> -inf) ; O = softmax(S)@V
// B=4, S=2048, H=1024.  bf16 MFMA path.
// R19: revert to R16 (191.7us best; R17 coop launch rejected, R18
//     producer-consumer poisoned coherence: 520us, MfmaUtil 5.4%).
//     Attack scores/pv GRID QUANTIZATION with plain launches:
//     scores 128x128 => ~544 active tiles on 512 slots (2 blk/CU @64KB)
//     = 2 rounds (53us for 27us of work). Now scores/pv = 128x64 tiles,
//     single-buffer m97 k-loop (R15-proven), 24KB LDS,
//     __launch_bounds__(256,4) -> 4 blk/CU = 1024 slots:
//     scores 1088 tiles -> ~2x13.5 = 27-32us; pv 1024 tiles -> 1 round ~15us.
//     qkv + prep = R16 verbatim.
// ---------------------------------------------------------------------------

typedef __attribute__((ext_vector_type(8))) short bf16x8;   // 8 bf16 = 4 VGPRs
typedef __attribute__((ext_vector_type(4))) float f32x4;

__device__ __forceinline__ void async_cp16(const void* g, void* l) {
  __builtin_amdgcn_global_load_lds(
      (const __attribute__((address_space(1))) void*)g,
      (__attribute__((address_space(3))) void*)l, 16, 0, 0);
}

__device__ __forceinline__ uint32_t laddr(const void* p) {
  return (uint32_t)(uintptr_t)(const __attribute__((address_space(3))) void*)p;
}

#define FENCE() asm volatile("" ::: "memory")
#define BAR()                           \
  do {                                  \
    FENCE();                            \
    __builtin_amdgcn_s_barrier();       \
    FENCE();                            \
  } while (0)
#define VMW(N) asm volatile("s_waitcnt vmcnt(" #N ")" ::: "memory")
#define LGKM0()                                            \
  do {                                                     \
    asm volatile("s_waitcnt lgkmcnt(0)" ::: "memory");     \
    __builtin_amdgcn_sched_barrier(0);                     \
  } while (0)
// asm ds_read_b128 with literal byte offset; no memory operand on purpose.
#define DSR(dst, a, OFF) \
  asm volatile("ds_read_b128 %0, %1 offset:" #OFF : "=v"(dst) : "v"(a))

// ------------------- merged prep: cvt + W^T + mask + zero -------------------
// grid: [0,8192) X cvt; [8192,11264) W transpose; [11264,11268) mask+rowsum0.
__global__ __launch_bounds__(256) void prep(
    const float* __restrict__ X, __hip_bfloat16* __restrict__ Xb,
    const float* __restrict__ W, __hip_bfloat16* __restrict__ Wt,
    const int* __restrict__ mask, int* __restrict__ idx,
    int* __restrict__ cnt, int* __restrict__ cnt_pad,
    float* __restrict__ rowsum) {
  const int b = blockIdx.x;
  const int tid = threadIdx.x;
  if (b < 8192) {
    int i = (b * 256 + tid) * 4;
    float4 f = *(const float4*)(X + i);
    __hip_bfloat16 o[4];
    o[0] = __float2bfloat16(f.x);
    o[1] = __float2bfloat16(f.y);
    o[2] = __float2bfloat16(f.z);
    o[3] = __float2bfloat16(f.w);
    *(ushort4*)(Xb + i) = *(const ushort4*)o;
    return;
  }
  if (b < 11264) {
    __shared__ float tile[32][33];
    const int t = b - 8192;
    const int bx = (t % 96) * 32;   // src col (of 3072)
    const int by = (t / 96) * 32;   // src row (of 1024)
    const int tx = tid & 31, ty = tid >> 5;
#pragma unroll
    for (int j = 0; j < 4; ++j)
      tile[ty + j * 8][tx] = W[(int64_t)(by + ty + j * 8) * 3072 + bx + tx];
    __syncthreads();
#pragma unroll
    for (int j = 0; j < 4; ++j)
      Wt[(int64_t)(bx + ty + j * 8) * 1024 + by + tx] =
          __float2bfloat16(tile[tx][ty + j * 8]);
    return;
  }
  {
    const int z = b - 11264;
    const int* mz = mask + z * 2048;
    int* iz = idx + z * 2048;
    const int lane = tid & 63, wave = tid >> 6;
    float* rs = rowsum + z * 2048;
#pragma unroll
    for (int j = 0; j < 8; ++j) rs[tid + j * 256] = 0.f;

    int keep[8];
    int local = 0;
#pragma unroll
    for (int j = 0; j < 8; ++j) {
      keep[j] = (mz[tid * 8 + j] == 0);
      local += keep[j];
    }
    int pre = local;  // inclusive wave scan
#pragma unroll
    for (int off = 1; off <= 32; off <<= 1) {
      int n = __shfl_up(pre, off, 64);
      if (lane >= off) pre += n;
    }
    __shared__ int wsum[4];
    if (lane == 63) wsum[wave] = pre;
    __syncthreads();
    int base = 0;
    for (int w = 0; w < wave; ++w) base += wsum[w];
    int excl = base + pre - local;
#pragma unroll
    for (int j = 0; j < 8; ++j)
      if (keep[j]) iz[excl++] = tid * 8 + j;
    if (tid == 255) {
      int tot = base + pre;
      cnt[z] = tot;
      cnt_pad[z] = (tot + 127) & ~127;
    }
  }
}

// --------------------------- merged Q+K+V GEMM -----------------------------
// grid (384, 1, B).  Swizzled flat id: xcd=f&7, loc=f>>3 in [0,48):
//   m_idx = (loc&7)*2 + (xcd>>2); n_idx = (loc>>3)*4 + (xcd&3) in [0,24)
// 128x128 tile, 256 thr, BK=64, dbuf prefetch, asm ds_read fragments.
__global__ __launch_bounds__(256) void gemm_qkv(
    const __hip_bfloat16* __restrict__ Xb, const __hip_bfloat16* __restrict__ Wt,
    const float* __restrict__ bias, const int* __restrict__ idx,
    const int* __restrict__ cnt, const int* __restrict__ cnt_pad,
    __hip_bfloat16* __restrict__ Q, __hip_bfloat16* __restrict__ Kc,
    __hip_bfloat16* __restrict__ Vt) {
  const int z = blockIdx.z;
  const int f = blockIdx.x;
  const int xcd = f & 7, loc = f >> 3;
  const int m0 = ((loc & 7) * 2 + (xcd >> 2)) * 128;
  const int n_idx = (loc >> 3) * 4 + (xcd & 3);
  const bool isQ = (n_idx < 8);
  if (!isQ && m0 >= cnt_pad[z]) return;
  const int n0 = (isQ ? n_idx : n_idx - 8) * 128;
  const __hip_bfloat16* A = Xb + (int64_t)z * 2048 * 1024;
  const __hip_bfloat16* Bt = Wt + (isQ ? 0 : (int64_t)1024 * 1024);
  const float* bv = bias + (isQ ? 0 : 1024);

  const int tid = threadIdx.x;
  const int wave = tid >> 6, lane = tid & 63;
  const int quad = lane >> 4, tr = lane & 15, t7 = tr & 7;
  const int wm = wave & 1, wn = wave >> 1;

  __shared__ __hip_bfloat16 ls[32768];

  const __hip_bfloat16* gsrc[8];
  int loff[8];
  {
    const int srow = lane >> 3;
    const int kcs = (((lane & 7) ^ srow) * 8);
    const int cz = isQ ? 0 : cnt[z];
    const int* idxz = idx + z * 2048;
#pragma unroll
    for (int cc = 0; cc < 8; ++cc) {
      int c = wave * 8 + cc;
      int isA = (c < 16);
      int cr = isA ? c : (c - 16);
      int row = cr * 8 + srow;
      if (isA) {
        int ar = m0 + row;
        if (!isQ) ar = (ar < cz) ? idxz[ar] : 0;
        gsrc[cc] = A + (int64_t)ar * 1024 + kcs;
      } else {
        gsrc[cc] = Bt + (int64_t)(n0 + row) * 1024 + kcs;
      }
      loff[cc] = (isA ? 0 : 8192) + cr * 512;
    }
  }

  uint32_t aAd[2][2], bBd[2][2];
  {
    uint32_t base = laddr(ls);
#pragma unroll
    for (int b = 0; b < 2; ++b)
#pragma unroll
      for (int w = 0; w < 2; ++w) {
        uint32_t col = (uint32_t)(((((w << 2) | quad)) ^ t7) * 16);
        aAd[b][w] = base + b * 32768 + (wm * 64 + tr) * 128 + col;
        bBd[b][w] = base + b * 32768 + 16384 + (wn * 64 + tr) * 128 + col;
      }
  }

  f32x4 acc[4][4];
#pragma unroll
  for (int mi = 0; mi < 4; ++mi)
#pragma unroll
    for (int ni = 0; ni < 4; ++ni) acc[mi][ni] = (f32x4){0.f, 0.f, 0.f, 0.f};

  bf16x8 af[4], bf[4];

#define STAGE(BUF, k0)                                            \
  do {                                                            \
    _Pragma("unroll") for (int cc = 0; cc < 8; ++cc)              \
        async_cp16(gsrc[cc] + (k0), ls + (BUF)*16384 + loff[cc]); \
  } while (0)
#define COMP(BUF)                                                             \
  do {                                                                        \
    _Pragma("unroll") for (int w = 0; w < 2; ++w) {                           \
      DSR(af[0], aAd[BUF][w], 0);                                             \
      DSR(af[1], aAd[BUF][w], 2048);                                          \
      DSR(af[2], aAd[BUF][w], 4096);                                          \
      DSR(af[3], aAd[BUF][w], 6144);                                          \
      DSR(bf[0], bBd[BUF][w], 0);                                             \
      DSR(bf[1], bBd[BUF][w], 2048);                                          \
      DSR(bf[2], bBd[BUF][w], 4096);                                          \
      DSR(bf[3], bBd[BUF][w], 6144);                                          \
      LGKM0();                                                                \
      _Pragma("unroll") for (int mi = 0; mi < 4; ++mi)                        \
          _Pragma("unroll") for (int ni = 0; ni < 4; ++ni) acc[mi][ni] =      \
              __builtin_amdgcn_mfma_f32_16x16x32_bf16(af[mi], bf[ni],         \
                                                      acc[mi][ni], 0, 0, 0);  \
    }                                                                         \
  } while (0)

  STAGE(0, 0);
  for (int it = 0; it < 8; ++it) {
    STAGE(1, (2 * it + 1) * 64);
    VMW(8); BAR();
    COMP(0);
    BAR();
    if (it < 7) {
      STAGE(0, (2 * it + 2) * 64);
      VMW(8);
    } else {
      VMW(0);
    }
    BAR();
    COMP(1);
    BAR();
  }
#undef STAGE
#undef COMP

  // Epilogue. D element (row,col) in 16x16 tile = (quad*4 + r, tr)  [m89]
  const int rowbase = m0 + wm * 64;
  const int colbase = n0 + wn * 64;
  if (isQ) {
    __hip_bfloat16* C = Q + (int64_t)z * 2048 * 1024;
#pragma unroll
    for (int ni = 0; ni < 4; ++ni) {
      int col = colbase + ni * 16 + tr;
      float bb = bv[col];
#pragma unroll
      for (int mi = 0; mi < 4; ++mi) {
        int row = rowbase + mi * 16 + quad * 4;
#pragma unroll
        for (int r = 0; r < 4; ++r)
          C[(int64_t)(row + r) * 1024 + col] =
              __float2bfloat16(acc[mi][ni][r] + bb);
      }
    }
  } else if (n0 < 1024) {  // K half
    __hip_bfloat16* C = Kc + (int64_t)z * 2048 * 1024;
#pragma unroll
    for (int ni = 0; ni < 4; ++ni) {
      int col = colbase + ni * 16 + tr;
      float bb = bv[col];
#pragma unroll
      for (int mi = 0; mi < 4; ++mi) {
        int row = rowbase + mi * 16 + quad * 4;
#pragma unroll
        for (int r = 0; r < 4; ++r)
          C[(int64_t)(row + r) * 1024 + col] =
              __float2bfloat16(acc[mi][ni][r] + bb);
      }
    }
  } else {  // V half -> LDS transpose -> coalesced Vt rows
    __syncthreads();
#pragma unroll
    for (int ni = 0; ni < 4; ++ni) {
      int cl = wn * 64 + ni * 16 + tr;  // block-local d
      float bb = bv[colbase + ni * 16 + tr];
#pragma unroll
      for (int mi = 0; mi < 4; ++mi) {
        int rl = wm * 64 + mi * 16 + quad * 4;  // block-local key
        __hip_bfloat16 h[4];
#pragma unroll
        for (int r = 0; r < 4; ++r) h[r] = __float2bfloat16(acc[mi][ni][r] + bb);
        *(ushort4*)(ls + cl * 136 + rl) = *(const ushort4*)h;
      }
    }
    __syncthreads();
    __hip_bfloat16* Vz = Vt + (int64_t)z * 1024 * 2048;
    const int d0 = n0 - 1024;
    const int seg = tid & 15;
#pragma unroll
    for (int p = 0; p < 8; ++p) {
      int d = p * 16 + (tid >> 4);
      bf16x8 v = *(const bf16x8*)(ls + d * 136 + seg * 8);
      *(bf16x8*)(Vz + (int64_t)(d0 + d) * 2048 + m0 + seg * 8) = v;
    }
  }
}

// ------------------------ scores GEMM + fused exp --------------------------
// e = exp2(scale2 * (Q@Kc^T)) bf16; cols >= cnt -> 0. Row sums -> atomicAdd.
// 128x64 tile, BK=64, SINGLE-buffer m97 loop, asm ds_read COMP, 24KB LDS,
// 4 blk/CU. grid (512,1,4): m_idx=(loc&7)*2+(xcd>>2), n_idx=(loc>>3)*4+(xcd&3).
__global__ __launch_bounds__(256, 4) void gemm_scores(
    const __hip_bfloat16* __restrict__ Qb, const __hip_bfloat16* __restrict__ Kc,
    __hip_bfloat16* __restrict__ Sc, float* __restrict__ rowsum,
    const int* __restrict__ cnt, const int* __restrict__ cnt_pad,
    float scale2) {
  const int z = blockIdx.z;
  const int f = blockIdx.x;
  const int xcd = f & 7, loc = f >> 3;
  const int m0 = ((loc & 7) * 2 + (xcd >> 2)) * 128;
  const int n0 = ((loc >> 3) * 4 + (xcd & 3)) * 64;
  if (n0 >= cnt_pad[z]) return;
  const __hip_bfloat16* A = Qb + (int64_t)z * 2048 * 1024;
  const __hip_bfloat16* Bt = Kc + (int64_t)z * 2048 * 1024;

  const int tid = threadIdx.x;
  const int wave = tid >> 6, lane = tid & 63;
  const int quad = lane >> 4, tr = lane & 15, t7 = tr & 7;
  const int wm = wave & 1, wn = wave >> 1;

  __shared__ __hip_bfloat16 ls[12288];  // A 8192 el + B 4096 el = 24KB

  // 24 chunks of 1KB: 0..15 = A, 16..23 = B. 6/wave.
  const __hip_bfloat16* gsrc[6];
  int loff[6];
  {
    const int srow = lane >> 3;
    const int kcs = (((lane & 7) ^ srow) * 8);
#pragma unroll
    for (int cc = 0; cc < 6; ++cc) {
      int c = wave * 6 + cc;
      int isA = (c < 16);
      int cr = isA ? c : (c - 16);
      int row = cr * 8 + srow;
      gsrc[cc] = isA ? (A + (int64_t)(m0 + row) * 1024 + kcs)
                     : (Bt + (int64_t)(n0 + row) * 1024 + kcs);
      loff[cc] = (isA ? 0 : 8192) + cr * 512;
    }
  }

  uint32_t aAd[2], bBd[2];
  {
    uint32_t base = laddr(ls);
#pragma unroll
    for (int w = 0; w < 2; ++w) {
      uint32_t col = (uint32_t)(((((w << 2) | quad)) ^ t7) * 16);
      aAd[w] = base + (wm * 64 + tr) * 128 + col;
      bBd[w] = base + 16384 + (wn * 32 + tr) * 128 + col;
    }
  }

  f32x4 acc[4][2];
#pragma unroll
  for (int mi = 0; mi < 4; ++mi)
#pragma unroll
    for (int ni = 0; ni < 2; ++ni) acc[mi][ni] = (f32x4){0.f, 0.f, 0.f, 0.f};

  bf16x8 af[4], bf[2];

#define STAGE(k0)                                     \
  do {                                                \
    _Pragma("unroll") for (int cc = 0; cc < 6; ++cc)  \
        async_cp16(gsrc[cc] + (k0), ls + loff[cc]);   \
  } while (0)
#define COMP()                                                                \
  do {                                                                        \
    _Pragma("unroll") for (int w = 0; w < 2; ++w) {                           \
      DSR(af[0], aAd[w], 0);                                                  \
      DSR(af[1], aAd[w], 2048);                                               \
      DSR(af[2], aAd[w], 4096);                                               \
      DSR(af[3], aAd[w], 6144);                                               \
      DSR(bf[0], bBd[w], 0);                                                  \
      DSR(bf[1], bBd[w], 2048);                                               \
      LGKM0();                                                                \
      _Pragma("unroll") for (int mi = 0; mi < 4; ++mi)                        \
          _Pragma("unroll") for (int ni = 0; ni < 2; ++ni) acc[mi][ni] =      \
              __builtin_amdgcn_mfma_f32_16x16x32_bf16(af[mi], bf[ni],         \
                                                      acc[mi][ni], 0, 0, 0);  \
    }                                                                         \
  } while (0)

  for (int t = 0; t < 16; ++t) {
    BAR();
    STAGE(t * 64);
    VMW(0);
    BAR();
    COMP();
  }
#undef STAGE
#undef COMP

  const int rowbase = m0 + wm * 64;
  const int colbase = n0 + wn * 32;
  const int cn = cnt[z];
  __hip_bfloat16* C = Sc + (int64_t)z * 2048 * 2048;

  float psum[4][4];
#pragma unroll
  for (int mi = 0; mi < 4; ++mi)
#pragma unroll
    for (int r = 0; r < 4; ++r) psum[mi][r] = 0.f;

#pragma unroll
  for (int ni = 0; ni < 2; ++ni) {
    int col = colbase + ni * 16 + tr;
    bool valid = (col < cn);
#pragma unroll
    for (int mi = 0; mi < 4; ++mi) {
      int row = rowbase + mi * 16 + quad * 4;
#pragma unroll
      for (int r = 0; r < 4; ++r) {
        float e = valid ? exp2f(acc[mi][ni][r] * scale2) : 0.f;
        C[(int64_t)(row + r) * 2048 + col] = __float2bfloat16(e);
        psum[mi][r] += e;
      }
    }
  }
#pragma unroll
  for (int off = 1; off <= 8; off <<= 1)
#pragma unroll
    for (int mi = 0; mi < 4; ++mi)
#pragma unroll
      for (int r = 0; r < 4; ++r)
        psum[mi][r] += __shfl_xor(psum[mi][r], off, 64);
  if (tr == 0) {
    float* rs = rowsum + z * 2048 + rowbase;
#pragma unroll
    for (int mi = 0; mi < 4; ++mi)
#pragma unroll
      for (int r = 0; r < 4; ++r)
        atomicAdd(&rs[mi * 16 + quad * 4 + r], psum[mi][r]);
  }
}

// --------------------------- PV GEMM + normalize ---------------------------
// out = (E @ Vt^T) / rowsum[row]  (fp32). K = cnt_pad[z]. 128x64 tile,
// single-buffer m97 loop, 24KB LDS, 4 blk/CU. grid (256,1,4).
__global__ __launch_bounds__(256, 4) void gemm_pv(
    const __hip_bfloat16* __restrict__ Sc, const __hip_bfloat16* __restrict__ Vt,
    float* __restrict__ out, const float* __restrict__ rowsum,
    const int* __restrict__ cnt_pad) {
  const int z = blockIdx.z;
  const int f = blockIdx.x;
  const int xcd = f & 7, loc = f >> 3;
  const int m0 = ((loc & 7) * 2 + (xcd >> 2)) * 128;
  const int n0 = ((loc >> 3) * 4 + (xcd & 3)) * 64;
  const int Ks = cnt_pad[z];
  const __hip_bfloat16* A = Sc + (int64_t)z * 2048 * 2048;
  const __hip_bfloat16* Bt = Vt + (int64_t)z * 1024 * 2048;

  const int tid = threadIdx.x;
  const int wave = tid >> 6, lane = tid & 63;
  const int quad = lane >> 4, tr = lane & 15, t7 = tr & 7;
  const int wm = wave & 1, wn = wave >> 1;

  __shared__ __hip_bfloat16 ls[12288];

  const __hip_bfloat16* gsrc[6];
  int loff[6];
  {
    const int srow = lane >> 3;
    const int kcs = (((lane & 7) ^ srow) * 8);
#pragma unroll
    for (int cc = 0; cc < 6; ++cc) {
      int c = wave * 6 + cc;
      int isA = (c < 16);
      int cr = isA ? c : (c - 16);
      int row = cr * 8 + srow;
      gsrc[cc] = isA ? (A + (int64_t)(m0 + row) * 2048 + kcs)
                     : (Bt + (int64_t)(n0 + row) * 2048 + kcs);
      loff[cc] = (isA ? 0 : 8192) + cr * 512;
    }
  }

  uint32_t aAd[2], bBd[2];
  {
    uint32_t base = laddr(ls);
#pragma unroll
    for (int w = 0; w < 2; ++w) {
      uint32_t col = (uint32_t)(((((w << 2) | quad)) ^ t7) * 16);
      aAd[w] = base + (wm * 64 + tr) * 128 + col;
      bBd[w] = base + 16384 + (wn * 32 + tr) * 128 + col;
    }
  }

  f32x4 acc[4][2];
#pragma unroll
  for (int mi = 0; mi < 4; ++mi)
#pragma unroll
    for (int ni = 0; ni < 2; ++ni) acc[mi][ni] = (f32x4){0.f, 0.f, 0.f, 0.f};

  bf16x8 af[4], bf[2];

#define STAGE(k0)                                     \
  do {                                                \
    _Pragma("unroll") for (int cc = 0; cc < 6; ++cc)  \
        async_cp16(gsrc[cc] + (k0), ls + loff[cc]);   \
  } while (0)
#define COMP()                                                                \
  do {                                                                        \
    _Pragma("unroll") for (int w = 0; w < 2; ++w) {                           \
      DSR(af[0], aAd[w], 0);                                                  \
      DSR(af[1], aAd[w], 2048);                                               \
      DSR(af[2], aAd[w], 4096);                                               \
      DSR(af[3], aAd[w], 6144);                                               \
      DSR(bf[0], bBd[w], 0);                                                  \
      DSR(bf[1], bBd[w], 2048);                                               \
      LGKM0();                                                                \
      _Pragma("unroll") for (int mi = 0; mi < 4; ++mi)                        \
          _Pragma("unroll") for (int ni = 0; ni < 2; ++ni) acc[mi][ni] =      \
              __builtin_amdgcn_mfma_f32_16x16x32_bf16(af[mi], bf[ni],         \
                                                      acc[mi][ni], 0, 0, 0);  \
    }                                                                         \
  } while (0)

  const int NT = Ks >> 6;  // K-tiles
  for (int t = 0; t < NT; ++t) {
    BAR();
    STAGE(t * 64);
    VMW(0);
    BAR();
    COMP();
  }
#undef STAGE
#undef COMP

  const int rowbase = m0 + wm * 64;
  const int colbase = n0 + wn * 32;
  const float* rs = rowsum + z * 2048 + rowbase;
  float invv[4][4];
#pragma unroll
  for (int mi = 0; mi < 4; ++mi)
#pragma unroll
    for (int r = 0; r < 4; ++r) invv[mi][r] = 1.0f / rs[mi * 16 + quad * 4 + r];

  float* C = out + (int64_t)z * 2048 * 1024;
#pragma unroll
  for (int ni = 0; ni < 2; ++ni) {
    int col = colbase + ni * 16 + tr;
#pragma unroll
    for (int mi = 0; mi < 4; ++mi) {
      int row = rowbase + mi * 16 + quad * 4;
#pragma unroll
      for (int r = 0; r < 4; ++r)
        C[(int64_t)(row + r) * 1024 + col] = acc[mi][ni][r] * invv[mi][r];
    }
  }
}

// ------------------------------- launcher ----------------------------------
extern "C" void kernel_launch(void* const* d_in, const int* in_sizes, int n_in,
                              void* d_out, int out_size, void* d_ws,
                              size_t ws_size, hipStream_t stream) {
  const float* X = (const float*)d_in[0];        // (4,2048,1024) fp32
  const int* mask = (const int*)d_in[1];         // (4,2048) bool->int32
  const float* W = (const float*)d_in[2];        // (1024,3072) fp32
  const float* bias = (const float*)d_in[3];     // (3072,) fp32
  float* out = (float*)d_out;                    // (4,2048,1024) fp32

  char* ws = (char*)d_ws;
  auto alloc = [&](size_t bytes) {
    char* p = ws;
    ws += (bytes + 255) & ~(size_t)255;
    return p;
  };
  __hip_bfloat16* Xb = (__hip_bfloat16*)alloc(8192ULL * 1024 * 2);      // 16.8 MB
  __hip_bfloat16* Wt = (__hip_bfloat16*)alloc(3072ULL * 1024 * 2);      //  6.3 MB
  __hip_bfloat16* Q = (__hip_bfloat16*)alloc(8192ULL * 1024 * 2);       // 16.8 MB
  __hip_bfloat16* Kc = (__hip_bfloat16*)alloc(4ULL * 2048 * 1024 * 2);  // 16.8 MB
  __hip_bfloat16* Vt = (__hip_bfloat16*)alloc(4ULL * 1024 * 2048 * 2);  // 16.8 MB
  __hip_bfloat16* Sc = (__hip_bfloat16*)alloc(4ULL * 2048 * 2048 * 2);  // 33.6 MB
  float* rowsum = (float*)alloc(8192ULL * 4);                           // 32 KB
  int* idx = (int*)alloc(4ULL * 2048 * 4);
  int* cnt = (int*)alloc(64);
  int* cnt_pad = (int*)alloc(64);

  // 1) merged prep: X->bf16, W->W^T bf16, mask->index list, rowsum=0
  prep<<<11268, 256, 0, stream>>>(X, Xb, W, Wt, mask, idx, cnt, cnt_pad,
                                  rowsum);
  // 2) merged Q + K + V^T (swizzled; V transposed via LDS in epilogue)
  gemm_qkv<<<dim3(384, 1, 4), 256, 0, stream>>>(Xb, Wt, bias, idx, cnt,
                                                cnt_pad, Q, Kc, Vt);
  // 3) E = exp2(log2e/32 * Q@Kc^T) -> bf16, rowsum += per-row sums  (128x64)
  gemm_scores<<<dim3(512, 1, 4), 256, 0, stream>>>(
      Q, Kc, Sc, rowsum, cnt, cnt_pad, 0.03125f * 1.4426950408889634f);
  // 4) out = (E @ Vt^T) / rowsum  (fp32, K = cnt_pad)  (128x64)
  gemm_pv<<<dim3(256, 1, 4), 256, 0, stream>>>(Sc, Vt, out, rowsum, cnt_pad);
}